// Round 1
// baseline (1113.056 us; speedup 1.0000x reference)
//
#include <hip/hip_runtime.h>
#include <math.h>

#define N 128
#define B 8
#define CI 32
#define CO 32
#define M1 4
#define M2 5
#define IK (CI*CO)       // 1024
#define IKP (IK*M1)      // 4096
#define IKQ (IK*M2)      // 5120
#define TWO_PI_F 6.2831853071795864769f

__device__ __forceinline__ float2 cmul(float2 a, float2 b){
    return make_float2(a.x*b.x - a.y*b.y, a.x*b.y + a.y*b.x);
}
__device__ __forceinline__ float2 cmadd(float2 acc, float2 a, float2 b){
    acc.x += a.x*b.x - a.y*b.y;
    acc.y += a.x*b.y + a.y*b.x;
    return acc;
}

// A1T[o][ik*M1+p] = 1/(i*2pi*f(o) - wp1[ik,p]); freq-major for contiguous per-o slices
__global__ void k_A1T(const float* wr_, const float* wi_, const float* t_, float2* A1T){
    int idx = blockIdx.x*256 + threadIdx.x;      // [0, N*IKP)
    int o   = idx >> 12;                          // /IKP
    int ikp = idx & (IKP-1);
    float d = t_[1]-t_[0];
    float invnd = 1.0f/((float)N*d);
    int kk = (o < N/2) ? o : o - N;
    float lam = TWO_PI_F * (float)kk * invnd;
    float dr = -wr_[ikp];
    float di = lam - wi_[ikp];
    float inv = 1.0f/(dr*dr + di*di);
    A1T[idx] = make_float2(dr*inv, -di*inv);
}

// A2[ikq][x] natural layout
__global__ void k_A2(const float* wr_, const float* wi_, const float* t_, float2* A2){
    int idx = blockIdx.x*256 + threadIdx.x;      // [0, IKQ*N)
    int ikq = idx >> 7; int xx = idx & (N-1);
    float d = t_[1]-t_[0];
    float invnd = 1.0f/((float)N*d);
    int kk = (xx < N/2) ? xx : xx - N;
    float lam = TWO_PI_F * (float)kk * invnd;
    float dr = -wr_[ikq];
    float di = lam - wi_[ikq];
    float inv = 1.0f/(dr*dr + di*di);
    A2[idx] = make_float2(dr*inv, -di*inv);
}

// E[ikp][y] = exp(wp[ikp] * t[y])  (works for E1 with IKP and E2 with IKQ)
__global__ void k_E(const float* wr_, const float* wi_, const float* t_, float2* E){
    int idx = blockIdx.x*256 + threadIdx.x;
    int ikp = idx >> 7; int y = idx & (N-1);
    float t = t_[y];
    float m = expf(wr_[ikp]*t);
    float s, c; sincosf(wi_[ikp]*t, &s, &c);
    E[idx] = make_float2(m*c, m*s);
}

// W2T[x][ik*M1+p] = sum_q wr[ik,p,q] * A2[ik,q,x]
__global__ void k_W2T(const float* wrr, const float* wri, const float2* A2, float2* W2T){
    int idx = blockIdx.x*256 + threadIdx.x;      // [0, IKP*N)
    int ikp = idx >> 7; int xx = idx & (N-1);
    int ik = ikp >> 2; int p = ikp & 3;
    float2 acc = make_float2(0.f,0.f);
    const float* wr0 = wrr + ik*(M1*M2) + p*M2;
    const float* wi0 = wri + ik*(M1*M2) + p*M2;
    const float2* a2 = A2 + (size_t)ik*(M2*N) + xx;
    #pragma unroll
    for(int q=0;q<M2;q++){
        float2 w = make_float2(wr0[q], wi0[q]);
        acc = cmadd(acc, w, a2[q*N]);
    }
    W2T[(size_t)xx*IKP + ikp] = acc;
}

// real-input row DFT: x[row][n] -> out[row][k], 2 rows per block
__global__ void __launch_bounds__(256) k_dft_rows_real(const float* x, float2* out){
    __shared__ float xr[256];
    __shared__ float2 tw[N];
    int t = threadIdx.x;
    size_t base = (size_t)blockIdx.x*256;
    xr[t] = x[base + t];
    if(t < N){ float s,c; sincosf(-(float)t*(TWO_PI_F/N), &s, &c); tw[t] = make_float2(c,s); }
    __syncthreads();
    int r = t >> 7; int kx = t & (N-1);
    const float* row = xr + r*N;
    float2 acc = make_float2(0.f,0.f);
    for(int xx=0; xx<N; xx++){
        float v = row[xx];
        float2 w = tw[(kx*xx)&(N-1)];
        acc.x += v*w.x; acc.y += v*w.y;
    }
    out[base + t] = acc;
}

// complex row inverse DFT with 1/N scale: in[row][k] -> out[row][x]
__global__ void __launch_bounds__(256) k_idft_rows(const float2* in, float2* out){
    __shared__ float2 rows[256];
    __shared__ float2 tw[N];
    int t = threadIdx.x;
    size_t base = (size_t)blockIdx.x*256;
    rows[t] = in[base + t];
    if(t < N){ float s,c; sincosf((float)t*(TWO_PI_F/N), &s, &c); tw[t] = make_float2(c,s); }
    __syncthreads();
    int r = t >> 7; int xo = t & (N-1);
    const float2* row = rows + r*N;
    float2 acc = make_float2(0.f,0.f);
    for(int k=0;k<N;k++){
        acc = cmadd(acc, row[k], tw[(k*xo)&(N-1)]);
    }
    const float sc = 1.0f/N;
    out[base + t] = make_float2(acc.x*sc, acc.y*sc);
}

// column DFT over 16-column tiles. SIGNPOS: 0 => e^{-i}, 1 => e^{+i}.
// REALOUT: write real part * (1/N) to outr, else complex to outc.
template<int SIGNPOS, int REALOUT>
__global__ void __launch_bounds__(256) k_cols(const float2* in, float2* outc, float* outr){
    __shared__ float2 tile[N][16];
    __shared__ float2 tw[N];
    int t = threadIdx.x;
    int img = blockIdx.x >> 3;
    int x0 = (blockIdx.x & 7) * 16;
    const float2* src = in + (size_t)img*N*N;
    #pragma unroll
    for(int j=0;j<8;j++){
        int l = t + 256*j;
        int y = l >> 4; int xc = l & 15;
        tile[y][xc] = src[y*N + x0 + xc];
    }
    if(t < N){
        float s,c; sincosf((SIGNPOS ? (float)t : -(float)t)*(TWO_PI_F/N), &s, &c);
        tw[t] = make_float2(c,s);
    }
    __syncthreads();
    #pragma unroll
    for(int nn=0; nn<8; nn++){
        int o = t + 256*nn;
        int ky = o >> 4; int xc = o & 15;
        float2 acc = make_float2(0.f,0.f);
        for(int y=0;y<N;y++){
            acc = cmadd(acc, tile[y][xc], tw[(ky*y)&(N-1)]);
        }
        if(REALOUT){
            outr[(size_t)img*N*N + ky*N + x0 + xc] = acc.x * (1.0f/N);
        } else {
            outc[(size_t)img*N*N + ky*N + x0 + xc] = acc;
        }
    }
}

// per frequency point: Hsum[ik] = sum_p A1T[o][ik,p]*W2T[x][ik,p]; res1[b,k] = sum_i alpha[b,i]*Hsum[i,k]
__global__ void __launch_bounds__(256) k_res1(const float2* alpha, const float2* A1T,
                                              const float2* W2T, float2* res1){
    __shared__ float2 aval[B*CI];   // 256
    __shared__ float2 hs[IK];       // 1024
    int t = threadIdx.x;
    int f = blockIdx.x;
    int o = f >> 7; int xx = f & (N-1);
    aval[t] = alpha[(size_t)t*(N*N) + o*N + xx];
    const float2* a1 = A1T + (size_t)o*IKP;
    const float2* w2 = W2T + (size_t)xx*IKP;
    #pragma unroll
    for(int nn=0;nn<4;nn++){
        int ik = t + 256*nn;
        float2 h = make_float2(0.f,0.f);
        #pragma unroll
        for(int p=0;p<M1;p++){
            h = cmadd(h, a1[ik*M1+p], w2[ik*M1+p]);
        }
        hs[ik] = h;
    }
    __syncthreads();
    int b = t >> 5; int k = t & 31;
    float2 acc = make_float2(0.f,0.f);
    const float2* av = aval + b*CI;
    #pragma unroll
    for(int i=0;i<CI;i++){
        acc = cmadd(acc, av[i], hs[i*CO + k]);
    }
    res1[((size_t)(b*CO + k))*(N*N) + o*N + xx] = acc;
}

// per (b,i,k): U[q] = sum_x alpha[b,i,o,x]*A2[ik,q,x]; S[p,q] = sum_o A1[ik,p,o]*U; res2 += wr*S
__global__ void __launch_bounds__(128) k_S_res2(const float2* alpha, const float2* A2,
                                                const float2* A1T, const float* wrr,
                                                const float* wri, float2* res2){
    __shared__ float2 A2s[M2*N];
    __shared__ float2 tile[N][17];
    __shared__ float red[N][41];
    int t = threadIdx.x;  // 0..127 == o
    int bid = blockIdx.x;
    int b = bid >> 10;
    int ik = bid & (IK-1);
    int i = ik >> 5;
    int k = ik & 31;
    const float2* asrc = alpha + ((size_t)(b*CI + i))*(N*N);
    #pragma unroll
    for(int j=0;j<M2;j++) A2s[t + 128*j] = A2[(size_t)ik*(M2*N) + t + 128*j];
    float2 U[M2];
    #pragma unroll
    for(int q=0;q<M2;q++) U[q]=make_float2(0.f,0.f);
    for(int cx=0; cx<8; cx++){
        __syncthreads();
        int x0 = cx*16;
        #pragma unroll
        for(int j=0;j<16;j++){
            int l = t + 128*j;
            int ol = l >> 4; int xc = l & 15;
            tile[ol][xc] = asrc[ol*N + x0 + xc];
        }
        __syncthreads();
        for(int xc=0; xc<16; xc++){
            float2 av = tile[t][xc];
            #pragma unroll
            for(int q=0;q<M2;q++){
                U[q] = cmadd(U[q], av, A2s[q*N + x0 + xc]);
            }
        }
    }
    const float2* a1 = A1T + (size_t)t*IKP + ik*M1;
    #pragma unroll
    for(int p=0;p<M1;p++){
        float2 a = a1[p];
        #pragma unroll
        for(int q=0;q<M2;q++){
            float2 c = cmul(a, U[q]);
            red[t][(p*M2+q)*2  ] = c.x;
            red[t][(p*M2+q)*2+1] = c.y;
        }
    }
    __syncthreads();
    if(t < M1*M2){
        float sr=0.f, si=0.f;
        for(int r=0;r<N;r++){ sr += red[r][2*t]; si += red[r][2*t+1]; }
        float2 w = make_float2(wrr[ik*(M1*M2)+t], wri[ik*(M1*M2)+t]);
        float2 v = cmul(w, make_float2(sr,si));
        float2* dst = res2 + (size_t)(b*CO + k)*(M1*M2) + t;
        atomicAdd(&dst->x, v.x);
        atomicAdd(&dst->y, v.y);
    }
}

// x2[b,j,y,x] += (1/N^2) * Re( sum_{c,p,q} res2[b,c,p,q]*E1[c,j,p,y]*E2[c,j,q,x] )
__global__ void __launch_bounds__(256) k_x2(const float2* res2, const float2* E1,
                                            const float2* E2, float* out){
    __shared__ float2 Wt[M1][N];
    __shared__ float2 E1s[M1][N];
    int t = threadIdx.x;
    int b = blockIdx.x >> 5; int j = blockIdx.x & 31;
    int xx = t & (N-1); int hb = t >> 7;
    float acc[64];
    #pragma unroll
    for(int r=0;r<64;r++) acc[r]=0.f;
    for(int c=0;c<CI;c++){
        int ikcj = c*CO + j;
        __syncthreads();
        #pragma unroll
        for(int s=0;s<2;s++){
            int e = t + 256*s;
            int pp = e >> 7; int xi = e & (N-1);
            float2 w = make_float2(0.f,0.f);
            const float2* r2 = res2 + (size_t)(b*CO + c)*(M1*M2) + pp*M2;
            const float2* e2 = E2 + ((size_t)ikcj*M2)*N + xi;
            #pragma unroll
            for(int q=0;q<M2;q++) w = cmadd(w, r2[q], e2[q*N]);
            Wt[pp][xi] = w;
            E1s[pp][xi] = E1[((size_t)ikcj*M1 + pp)*N + xi];
        }
        __syncthreads();
        float2 wreg[M1];
        #pragma unroll
        for(int p=0;p<M1;p++) wreg[p] = Wt[p][xx];
        #pragma unroll
        for(int r=0;r<64;r++){
            int y = 2*r + hb;
            float s = 0.f;
            #pragma unroll
            for(int p=0;p<M1;p++){
                float2 e = E1s[p][y];
                s += e.x*wreg[p].x - e.y*wreg[p].y;
            }
            acc[r] += s;
        }
    }
    const float sc = 1.0f/((float)N*(float)N);
    size_t base = (size_t)(b*CO + j)*(N*N);
    #pragma unroll
    for(int r=0;r<64;r++){
        size_t idx = base + (size_t)(2*r+hb)*N + xx;
        out[idx] += acc[r]*sc;
    }
}

extern "C" void kernel_launch(void* const* d_in, const int* in_sizes, int n_in,
                              void* d_out, int out_size, void* d_ws, size_t ws_size,
                              hipStream_t stream){
    const float* x    = (const float*)d_in[0];
    const float* wp1r = (const float*)d_in[1];
    const float* wp1i = (const float*)d_in[2];
    const float* wp2r = (const float*)d_in[3];
    const float* wp2i = (const float*)d_in[4];
    const float* wrr  = (const float*)d_in[5];
    const float* wri  = (const float*)d_in[6];
    const float* ty   = (const float*)d_in[7];
    const float* tx   = (const float*)d_in[8];
    float* out = (float*)d_out;
    float2* ws = (float2*)d_ws;

    const size_t NCIMG = (size_t)B*CI*N*N;        // 4194304 complexes
    float2* bufA  = ws;                           // alphaX, later Z
    float2* alpha = bufA  + NCIMG;
    float2* res1  = alpha + NCIMG;
    float2* A1T   = res1  + NCIMG;                // N*IKP
    float2* A2    = A1T   + (size_t)N*IKP;        // IKQ*N
    float2* W2T   = A2    + (size_t)IKQ*N;        // N*IKP
    float2* E1    = W2T   + (size_t)N*IKP;        // IKP*N
    float2* E2    = E1    + (size_t)IKP*N;        // IKQ*N
    float2* res2  = E2    + (size_t)IKQ*N;        // B*CO*M1*M2

    k_A1T<<<(N*IKP)/256, 256, 0, stream>>>(wp1r, wp1i, ty, A1T);
    k_E  <<<(IKP*N)/256, 256, 0, stream>>>(wp1r, wp1i, ty, E1);
    k_A2 <<<(IKQ*N)/256, 256, 0, stream>>>(wp2r, wp2i, tx, A2);
    k_E  <<<(IKQ*N)/256, 256, 0, stream>>>(wp2r, wp2i, tx, E2);
    k_W2T<<<(IKP*N)/256, 256, 0, stream>>>(wrr, wri, A2, W2T);

    k_dft_rows_real<<<(B*CI*N*N)/256, 256, 0, stream>>>(x, bufA);
    k_cols<0,0><<<B*CI*8, 256, 0, stream>>>(bufA, alpha, nullptr);

    hipMemsetAsync(res2, 0, (size_t)B*CO*M1*M2*sizeof(float2), stream);
    k_res1<<<N*N, 256, 0, stream>>>(alpha, A1T, W2T, res1);
    k_S_res2<<<B*CI*CO, 128, 0, stream>>>(alpha, A2, A1T, wrr, wri, res2);

    k_idft_rows<<<(B*CO*N*N)/256, 256, 0, stream>>>(res1, bufA);
    k_cols<1,1><<<B*CO*8, 256, 0, stream>>>(bufA, nullptr, out);
    k_x2<<<B*CO, 256, 0, stream>>>(res2, E1, E2, out);
}

// Round 2
// 1080.338 us; speedup vs baseline: 1.0303x; 1.0303x over previous
//
#include <hip/hip_runtime.h>
#include <math.h>

#define N 128
#define B 8
#define CI 32
#define CO 32
#define M1 4
#define M2 5
#define KG 8
#define IK (CI*CO)       // 1024
#define IKP (IK*M1)      // 4096
#define IKQ (IK*M2)      // 5120
#define TWO_PI_F 6.2831853071795864769f

__device__ __forceinline__ float2 cmul(float2 a, float2 b){
    return make_float2(a.x*b.x - a.y*b.y, a.x*b.y + a.y*b.x);
}
__device__ __forceinline__ float2 cmadd(float2 acc, float2 a, float2 b){
    acc.x += a.x*b.x - a.y*b.y;
    acc.y += a.x*b.y + a.y*b.x;
    return acc;
}

// A1T[o][ik*M1+p] = 1/(i*2pi*f(o) - wp1[ik,p]); freq-major for contiguous per-o slices
__global__ void k_A1T(const float* wr_, const float* wi_, const float* t_, float2* A1T){
    int idx = blockIdx.x*256 + threadIdx.x;      // [0, N*IKP)
    int o   = idx >> 12;                          // /IKP
    int ikp = idx & (IKP-1);
    float d = t_[1]-t_[0];
    float invnd = 1.0f/((float)N*d);
    int kk = (o < N/2) ? o : o - N;
    float lam = TWO_PI_F * (float)kk * invnd;
    float dr = -wr_[ikp];
    float di = lam - wi_[ikp];
    float inv = 1.0f/(dr*dr + di*di);
    A1T[idx] = make_float2(dr*inv, -di*inv);
}

// A2[ikq][x] natural layout
__global__ void k_A2(const float* wr_, const float* wi_, const float* t_, float2* A2){
    int idx = blockIdx.x*256 + threadIdx.x;      // [0, IKQ*N)
    int ikq = idx >> 7; int xx = idx & (N-1);
    float d = t_[1]-t_[0];
    float invnd = 1.0f/((float)N*d);
    int kk = (xx < N/2) ? xx : xx - N;
    float lam = TWO_PI_F * (float)kk * invnd;
    float dr = -wr_[ikq];
    float di = lam - wi_[ikq];
    float inv = 1.0f/(dr*dr + di*di);
    A2[idx] = make_float2(dr*inv, -di*inv);
}

// E[ikp][y] = exp(wp[ikp] * t[y])  (works for E1 with IKP and E2 with IKQ)
__global__ void k_E(const float* wr_, const float* wi_, const float* t_, float2* E){
    int idx = blockIdx.x*256 + threadIdx.x;
    int ikp = idx >> 7; int y = idx & (N-1);
    float t = t_[y];
    float m = expf(wr_[ikp]*t);
    float s, c; sincosf(wi_[ikp]*t, &s, &c);
    E[idx] = make_float2(m*c, m*s);
}

// W2T[x][ik*M1+p] = sum_q wr[ik,p,q] * A2[ik,q,x]
__global__ void k_W2T(const float* wrr, const float* wri, const float2* A2, float2* W2T){
    int idx = blockIdx.x*256 + threadIdx.x;      // [0, IKP*N)
    int ikp = idx >> 7; int xx = idx & (N-1);
    int ik = ikp >> 2; int p = ikp & 3;
    float2 acc = make_float2(0.f,0.f);
    const float* wr0 = wrr + ik*(M1*M2) + p*M2;
    const float* wi0 = wri + ik*(M1*M2) + p*M2;
    const float2* a2 = A2 + (size_t)ik*(M2*N) + xx;
    #pragma unroll
    for(int q=0;q<M2;q++){
        float2 w = make_float2(wr0[q], wi0[q]);
        acc = cmadd(acc, w, a2[q*N]);
    }
    W2T[(size_t)xx*IKP + ikp] = acc;
}

// real-input row DFT: x[row][n] -> out[row][k], 2 rows per block
__global__ void __launch_bounds__(256) k_dft_rows_real(const float* x, float2* out){
    __shared__ float xr[256];
    __shared__ float2 tw[N];
    int t = threadIdx.x;
    size_t base = (size_t)blockIdx.x*256;
    xr[t] = x[base + t];
    if(t < N){ float s,c; sincosf(-(float)t*(TWO_PI_F/N), &s, &c); tw[t] = make_float2(c,s); }
    __syncthreads();
    int r = t >> 7; int kx = t & (N-1);
    const float* row = xr + r*N;
    float2 acc = make_float2(0.f,0.f);
    for(int xx=0; xx<N; xx++){
        float v = row[xx];
        float2 w = tw[(kx*xx)&(N-1)];
        acc.x += v*w.x; acc.y += v*w.y;
    }
    out[base + t] = acc;
}

// complex row inverse DFT with 1/N scale: in[row][k] -> out[row][x]
__global__ void __launch_bounds__(256) k_idft_rows(const float2* in, float2* out){
    __shared__ float2 rows[256];
    __shared__ float2 tw[N];
    int t = threadIdx.x;
    size_t base = (size_t)blockIdx.x*256;
    rows[t] = in[base + t];
    if(t < N){ float s,c; sincosf((float)t*(TWO_PI_F/N), &s, &c); tw[t] = make_float2(c,s); }
    __syncthreads();
    int r = t >> 7; int xo = t & (N-1);
    const float2* row = rows + r*N;
    float2 acc = make_float2(0.f,0.f);
    for(int k=0;k<N;k++){
        acc = cmadd(acc, row[k], tw[(k*xo)&(N-1)]);
    }
    const float sc = 1.0f/N;
    out[base + t] = make_float2(acc.x*sc, acc.y*sc);
}

// column DFT over 16-column tiles. SIGNPOS: 0 => e^{-i}, 1 => e^{+i}.
// REALOUT: write real part * (1/N) to outr, else complex to outc.
template<int SIGNPOS, int REALOUT>
__global__ void __launch_bounds__(256) k_cols(const float2* in, float2* outc, float* outr){
    __shared__ float2 tile[N][16];
    __shared__ float2 tw[N];
    int t = threadIdx.x;
    int img = blockIdx.x >> 3;
    int x0 = (blockIdx.x & 7) * 16;
    const float2* src = in + (size_t)img*N*N;
    #pragma unroll
    for(int j=0;j<8;j++){
        int l = t + 256*j;
        int y = l >> 4; int xc = l & 15;
        tile[y][xc] = src[y*N + x0 + xc];
    }
    if(t < N){
        float s,c; sincosf((SIGNPOS ? (float)t : -(float)t)*(TWO_PI_F/N), &s, &c);
        tw[t] = make_float2(c,s);
    }
    __syncthreads();
    #pragma unroll
    for(int nn=0; nn<8; nn++){
        int o = t + 256*nn;
        int ky = o >> 4; int xc = o & 15;
        float2 acc = make_float2(0.f,0.f);
        for(int y=0;y<N;y++){
            acc = cmadd(acc, tile[y][xc], tw[(ky*y)&(N-1)]);
        }
        if(REALOUT){
            outr[(size_t)img*N*N + ky*N + x0 + xc] = acc.x * (1.0f/N);
        } else {
            outc[(size_t)img*N*N + ky*N + x0 + xc] = acc;
        }
    }
}

// per frequency point: Hsum[ik] = sum_p A1T[o][ik,p]*W2T[x][ik,p]; res1[b,k] = sum_i alpha[b,i]*Hsum[i,k]
__global__ void __launch_bounds__(256) k_res1(const float2* alpha, const float2* A1T,
                                              const float2* W2T, float2* res1){
    __shared__ float2 aval[B*CI];   // 256
    __shared__ float2 hs[IK];       // 1024
    int t = threadIdx.x;
    int f = blockIdx.x;
    int o = f >> 7; int xx = f & (N-1);
    aval[t] = alpha[(size_t)t*(N*N) + o*N + xx];
    const float2* a1 = A1T + (size_t)o*IKP;
    const float2* w2 = W2T + (size_t)xx*IKP;
    #pragma unroll
    for(int nn=0;nn<4;nn++){
        int ik = t + 256*nn;
        float2 h = make_float2(0.f,0.f);
        #pragma unroll
        for(int p=0;p<M1;p++){
            h = cmadd(h, a1[ik*M1+p], w2[ik*M1+p]);
        }
        hs[ik] = h;
    }
    __syncthreads();
    int b = t >> 5; int k = t & 31;
    float2 acc = make_float2(0.f,0.f);
    const float2* av = aval + b*CI;
    #pragma unroll
    for(int i=0;i<CI;i++){
        acc = cmadd(acc, av[i], hs[i*CO + k]);
    }
    res1[((size_t)(b*CO + k))*(N*N) + o*N + xx] = acc;
}

// per (b,i,kgroup of KG=8): U[kk][q] = sum_x alpha[b,i,o,x]*A2[ik,q,x] per o (=thread);
// then S[kk][p][q] = sum_o A1[ik,p,o]*U; res2 += wr*S (atomics over i).
// LDS pool (25088 B): alpha tile planes [128][17]x2 + A2 chunk [16][40]; reused as red[128][21].
__global__ void __launch_bounds__(128) k_S_res2(const float2* alpha, const float2* A2,
                                                const float2* A1T, const float* wrr,
                                                const float* wri, float2* res2){
    __shared__ __align__(16) unsigned char smem_pool[25088];
    float*  tre = (float*)smem_pool;              // [128][17] floats (stride 17: 2-way banks only)
    float*  tim = tre + 128*17;                   // [128][17]
    float2* A2c = (float2*)(tim + 128*17);        // [16][40] float2
    float2* red = (float2*)smem_pool;             // [128][21] float2, reused after U-phase

    int t = threadIdx.x;           // o
    int bid = blockIdx.x;          // (b*CI + i)*4 + kg
    int kg = bid & 3;
    int i  = (bid >> 2) & (CI-1);
    int b  = bid >> 7;
    int k0 = kg*KG;
    const float2* asrc = alpha + ((size_t)(b*CI + i))*(N*N);

    float2 U[KG*M2];
    #pragma unroll
    for(int r=0;r<KG*M2;r++) U[r] = make_float2(0.f,0.f);

    for(int cx=0; cx<8; cx++){
        int x0 = cx*16;
        __syncthreads();
        // stage 16 alpha columns, split re/im planes (conflict-free reads)
        #pragma unroll
        for(int j=0;j<16;j++){
            int l = t + 128*j;
            int ol = l >> 4, xc = l & 15;
            float2 v = asrc[ol*N + x0 + xc];
            tre[ol*17+xc] = v.x;
            tim[ol*17+xc] = v.y;
        }
        // stage A2 chunk: A2c[xc][r], r = kk*M2+q
        #pragma unroll
        for(int s=0;s<5;s++){
            int e = t + 128*s;                    // 640 = 16*40
            int xc = e / 40, r = e - xc*40;
            int kk = r / M2, q = r - kk*M2;
            A2c[xc*40 + r] = A2[((size_t)(i*CO + k0 + kk))*(M2*N) + q*N + x0 + xc];
        }
        __syncthreads();
        #pragma unroll 2
        for(int xc=0; xc<16; xc++){
            float2 av = make_float2(tre[t*17+xc], tim[t*17+xc]);
            const float2* a2row = A2c + xc*40;    // broadcast reads (wave-uniform addr)
            #pragma unroll
            for(int r=0;r<KG*M2;r++) U[r] = cmadd(U[r], av, a2row[r]);
        }
    }
    __syncthreads();

    // S-phase: per kk, weighted reduce over o via LDS
    const float2* A1p = A1T + (size_t)t*IKP + (size_t)(i*CO + k0)*M1;
    #pragma unroll
    for(int kk=0;kk<KG;kk++){
        float2 a1kp[M1];
        #pragma unroll
        for(int p=0;p<M1;p++) a1kp[p] = A1p[kk*M1+p];
        #pragma unroll
        for(int p=0;p<M1;p++){
            #pragma unroll
            for(int q=0;q<M2;q++){
                red[t*21 + p*M2+q] = cmul(a1kp[p], U[kk*M2+q]);
            }
        }
        __syncthreads();
        // fold 128 rows -> 32 rows (each (r,pq) owned by exactly one thread)
        #pragma unroll
        for(int s=0;s<5;s++){
            int e = t + 128*s;                    // 640 = 32*20
            int r = e / 20, pq = e - r*20;
            float2 acc = red[r*21+pq];
            float2 v1 = red[(r+32)*21+pq];
            float2 v2 = red[(r+64)*21+pq];
            float2 v3 = red[(r+96)*21+pq];
            acc.x += v1.x + v2.x + v3.x;
            acc.y += v1.y + v2.y + v3.y;
            red[r*21+pq] = acc;
        }
        __syncthreads();
        if(t < M1*M2){
            float2 S = make_float2(0.f,0.f);
            for(int r=0;r<32;r++){ S.x += red[r*21+t].x; S.y += red[r*21+t].y; }
            int ik = i*CO + k0 + kk;
            float2 w = make_float2(wrr[ik*(M1*M2)+t], wri[ik*(M1*M2)+t]);
            float2 v = cmul(w, S);
            float2* dst = res2 + (size_t)(b*CO + k0 + kk)*(M1*M2) + t;
            atomicAdd(&dst->x, v.x);
            atomicAdd(&dst->y, v.y);
        }
        __syncthreads();
    }
}

// x2[b,j,y,x] += (1/N^2) * Re( sum_{c,p,q} res2[b,c,p,q]*E1[c,j,p,y]*E2[c,j,q,x] )
__global__ void __launch_bounds__(256) k_x2(const float2* res2, const float2* E1,
                                            const float2* E2, float* out){
    __shared__ float2 Wt[M1][N];
    __shared__ float2 E1s[M1][N];
    int t = threadIdx.x;
    int b = blockIdx.x >> 5; int j = blockIdx.x & 31;
    int xx = t & (N-1); int hb = t >> 7;
    float acc[64];
    #pragma unroll
    for(int r=0;r<64;r++) acc[r]=0.f;
    for(int c=0;c<CI;c++){
        int ikcj = c*CO + j;
        __syncthreads();
        #pragma unroll
        for(int s=0;s<2;s++){
            int e = t + 256*s;
            int pp = e >> 7; int xi = e & (N-1);
            float2 w = make_float2(0.f,0.f);
            const float2* r2 = res2 + (size_t)(b*CO + c)*(M1*M2) + pp*M2;
            const float2* e2 = E2 + ((size_t)ikcj*M2)*N + xi;
            #pragma unroll
            for(int q=0;q<M2;q++) w = cmadd(w, r2[q], e2[q*N]);
            Wt[pp][xi] = w;
            E1s[pp][xi] = E1[((size_t)ikcj*M1 + pp)*N + xi];
        }
        __syncthreads();
        float2 wreg[M1];
        #pragma unroll
        for(int p=0;p<M1;p++) wreg[p] = Wt[p][xx];
        #pragma unroll
        for(int r=0;r<64;r++){
            int y = 2*r + hb;
            float s = 0.f;
            #pragma unroll
            for(int p=0;p<M1;p++){
                float2 e = E1s[p][y];
                s += e.x*wreg[p].x - e.y*wreg[p].y;
            }
            acc[r] += s;
        }
    }
    const float sc = 1.0f/((float)N*(float)N);
    size_t base = (size_t)(b*CO + j)*(N*N);
    #pragma unroll
    for(int r=0;r<64;r++){
        size_t idx = base + (size_t)(2*r+hb)*N + xx;
        out[idx] += acc[r]*sc;
    }
}

extern "C" void kernel_launch(void* const* d_in, const int* in_sizes, int n_in,
                              void* d_out, int out_size, void* d_ws, size_t ws_size,
                              hipStream_t stream){
    const float* x    = (const float*)d_in[0];
    const float* wp1r = (const float*)d_in[1];
    const float* wp1i = (const float*)d_in[2];
    const float* wp2r = (const float*)d_in[3];
    const float* wp2i = (const float*)d_in[4];
    const float* wrr  = (const float*)d_in[5];
    const float* wri  = (const float*)d_in[6];
    const float* ty   = (const float*)d_in[7];
    const float* tx   = (const float*)d_in[8];
    float* out = (float*)d_out;
    float2* ws = (float2*)d_ws;

    const size_t NCIMG = (size_t)B*CI*N*N;        // 4194304 complexes
    float2* bufA  = ws;                           // alphaX, later Z
    float2* alpha = bufA  + NCIMG;
    float2* res1  = alpha + NCIMG;
    float2* A1T   = res1  + NCIMG;                // N*IKP
    float2* A2    = A1T   + (size_t)N*IKP;        // IKQ*N
    float2* W2T   = A2    + (size_t)IKQ*N;        // N*IKP
    float2* E1    = W2T   + (size_t)N*IKP;        // IKP*N
    float2* E2    = E1    + (size_t)IKP*N;        // IKQ*N
    float2* res2  = E2    + (size_t)IKQ*N;        // B*CO*M1*M2

    k_A1T<<<(N*IKP)/256, 256, 0, stream>>>(wp1r, wp1i, ty, A1T);
    k_E  <<<(IKP*N)/256, 256, 0, stream>>>(wp1r, wp1i, ty, E1);
    k_A2 <<<(IKQ*N)/256, 256, 0, stream>>>(wp2r, wp2i, tx, A2);
    k_E  <<<(IKQ*N)/256, 256, 0, stream>>>(wp2r, wp2i, tx, E2);
    k_W2T<<<(IKP*N)/256, 256, 0, stream>>>(wrr, wri, A2, W2T);

    k_dft_rows_real<<<(B*CI*N*N)/256, 256, 0, stream>>>(x, bufA);
    k_cols<0,0><<<B*CI*8, 256, 0, stream>>>(bufA, alpha, nullptr);

    hipMemsetAsync(res2, 0, (size_t)B*CO*M1*M2*sizeof(float2), stream);
    k_res1<<<N*N, 256, 0, stream>>>(alpha, A1T, W2T, res1);
    k_S_res2<<<B*CI*(CO/KG), 128, 0, stream>>>(alpha, A2, A1T, wrr, wri, res2);

    k_idft_rows<<<(B*CO*N*N)/256, 256, 0, stream>>>(res1, bufA);
    k_cols<1,1><<<B*CO*8, 256, 0, stream>>>(bufA, nullptr, out);
    k_x2<<<B*CO, 256, 0, stream>>>(res2, E1, E2, out);
}

// Round 3
// 707.332 us; speedup vs baseline: 1.5736x; 1.5273x over previous
//
#include <hip/hip_runtime.h>
#include <math.h>

#define N 128
#define B 8
#define CI 32
#define CO 32
#define M1 4
#define M2 5
#define KG 8
#define IK (CI*CO)       // 1024
#define IKP (IK*M1)      // 4096
#define IKQ (IK*M2)      // 5120
#define TWO_PI_F 6.2831853071795864769f

__device__ __forceinline__ float2 cmul(float2 a, float2 b){
    return make_float2(a.x*b.x - a.y*b.y, a.x*b.y + a.y*b.x);
}
__device__ __forceinline__ float2 cmadd(float2 acc, float2 a, float2 b){
    acc.x += a.x*b.x - a.y*b.y;
    acc.y += a.x*b.y + a.y*b.x;
    return acc;
}

// A1T[o][ik*M1+p] = 1/(i*2pi*f(o) - wp1[ik,p]); freq-major for contiguous per-o slices
__global__ void k_A1T(const float* wr_, const float* wi_, const float* t_, float2* A1T){
    int idx = blockIdx.x*256 + threadIdx.x;      // [0, N*IKP)
    int o   = idx >> 12;                          // /IKP
    int ikp = idx & (IKP-1);
    float d = t_[1]-t_[0];
    float invnd = 1.0f/((float)N*d);
    int kk = (o < N/2) ? o : o - N;
    float lam = TWO_PI_F * (float)kk * invnd;
    float dr = -wr_[ikp];
    float di = lam - wi_[ikp];
    float inv = 1.0f/(dr*dr + di*di);
    A1T[idx] = make_float2(dr*inv, -di*inv);
}

// A2[ikq][x] natural layout
__global__ void k_A2(const float* wr_, const float* wi_, const float* t_, float2* A2){
    int idx = blockIdx.x*256 + threadIdx.x;      // [0, IKQ*N)
    int ikq = idx >> 7; int xx = idx & (N-1);
    float d = t_[1]-t_[0];
    float invnd = 1.0f/((float)N*d);
    int kk = (xx < N/2) ? xx : xx - N;
    float lam = TWO_PI_F * (float)kk * invnd;
    float dr = -wr_[ikq];
    float di = lam - wi_[ikq];
    float inv = 1.0f/(dr*dr + di*di);
    A2[idx] = make_float2(dr*inv, -di*inv);
}

// E[ikp][y] = exp(wp[ikp] * t[y])
__global__ void k_E(const float* wr_, const float* wi_, const float* t_, float2* E){
    int idx = blockIdx.x*256 + threadIdx.x;
    int ikp = idx >> 7; int y = idx & (N-1);
    float t = t_[y];
    float m = expf(wr_[ikp]*t);
    float s, c; sincosf(wi_[ikp]*t, &s, &c);
    E[idx] = make_float2(m*c, m*s);
}

// W2T[x][ik*M1+p] = sum_q wr[ik,p,q] * A2[ik,q,x]
__global__ void k_W2T(const float* wrr, const float* wri, const float2* A2, float2* W2T){
    int idx = blockIdx.x*256 + threadIdx.x;      // [0, IKP*N)
    int ikp = idx >> 7; int xx = idx & (N-1);
    int ik = ikp >> 2; int p = ikp & 3;
    float2 acc = make_float2(0.f,0.f);
    const float* wr0 = wrr + ik*(M1*M2) + p*M2;
    const float* wi0 = wri + ik*(M1*M2) + p*M2;
    const float2* a2 = A2 + (size_t)ik*(M2*N) + xx;
    #pragma unroll
    for(int q=0;q<M2;q++){
        float2 w = make_float2(wr0[q], wi0[q]);
        acc = cmadd(acc, w, a2[q*N]);
    }
    W2T[(size_t)xx*IKP + ikp] = acc;
}

// ---------- four-step FFT, 128 = 16 x 8 ----------
// X[c+16d] = sum_b W128^{bc} W8^{bd} ( sum_a x[8a+b] W16^{ac} ),  W = e^{sgn*2pi i/128}
// Stage1 thread owns (line, b, h): computes c = 8h+cc, cc=0..7, with (-1)^{ah} input fold.
// All twiddle indices compile-time; LDS strides padded (<=2-way aliasing, free).

// rows: 16 contiguous 128-lines per block
template<int SIGNPOS, int REALIN, int SCALE>
__global__ void __launch_bounds__(256) k_fft_rows(const void* in_, float2* out){
    const float sgn = SIGNPOS ? 1.0f : -1.0f;
    __shared__ float tre[16*132];
    __shared__ float tim_[16*132];
    __shared__ float zre[16*136];
    __shared__ float zim[16*136];
    int t = threadIdx.x;
    size_t row0 = (size_t)blockIdx.x * 16;

    if(REALIN){
        const float* src = (const float*)in_ + row0*N;
        #pragma unroll
        for(int j=0;j<8;j++){
            int idx = t + 256*j; int r = idx>>7, cl = idx&127;
            tre[r*132+cl] = src[idx];
        }
    } else {
        const float2* src = (const float2*)in_ + row0*N;
        #pragma unroll
        for(int j=0;j<8;j++){
            int idx = t + 256*j; int r = idx>>7, cl = idx&127;
            float2 v = src[idx];
            tre[r*132+cl] = v.x; tim_[r*132+cl] = v.y;
        }
    }
    float t16c[16], t16s[16];
    #pragma unroll
    for(int j=0;j<16;j++){ float s,c; sincosf(sgn*(TWO_PI_F/16.f)*(float)j, &s,&c); t16c[j]=c; t16s[j]=s; }
    __syncthreads();

    int r = t>>4, u = t&15, b = u&7, h = u>>3;
    float xr[16], xi[16];
    #pragma unroll
    for(int a=0;a<16;a++){
        float vr = tre[r*132 + 8*a + b];
        float vi = REALIN ? 0.f : tim_[r*132 + 8*a + b];
        if(h && (a&1)){ vr = -vr; vi = -vi; }
        xr[a]=vr; xi[a]=vi;
    }
    #pragma unroll
    for(int cc=0; cc<8; cc++){
        float yr=0.f, yi=0.f;
        #pragma unroll
        for(int a=0;a<16;a++){
            int j = (a*cc)&15;
            if(REALIN){
                yr += xr[a]*t16c[j];
                yi += xr[a]*t16s[j];
            } else {
                yr += xr[a]*t16c[j] - xi[a]*t16s[j];
                yi += xr[a]*t16s[j] + xi[a]*t16c[j];
            }
        }
        int c = 8*h + cc;
        float s,co; sincosf(sgn*(TWO_PI_F/128.f)*(float)(b*c), &s,&co);
        zre[r*136 + b*17 + c] = yr*co - yi*s;
        zim[r*136 + b*17 + c] = yr*s + yi*co;
    }
    __syncthreads();

    float t8c[8], t8s[8];
    #pragma unroll
    for(int j=0;j<8;j++){ float s,c; sincosf(sgn*(TWO_PI_F/8.f)*(float)j, &s,&c); t8c[j]=c; t8s[j]=s; }
    int r2 = t>>4, c2 = t&15;
    float zr_[8], zi_[8];
    #pragma unroll
    for(int bb=0;bb<8;bb++){ zr_[bb]=zre[r2*136 + bb*17 + c2]; zi_[bb]=zim[r2*136 + bb*17 + c2]; }
    float2* dst = out + (row0 + r2)*N;
    #pragma unroll
    for(int d=0; d<8; d++){
        float Xr=0.f, Xi=0.f;
        #pragma unroll
        for(int bb=0;bb<8;bb++){
            int j=(bb*d)&7;
            Xr += zr_[bb]*t8c[j] - zi_[bb]*t8s[j];
            Xi += zr_[bb]*t8s[j] + zi_[bb]*t8c[j];
        }
        if(SCALE){ Xr *= (1.f/128.f); Xi *= (1.f/128.f); }
        dst[c2 + 16*d] = make_float2(Xr, Xi);
    }
}

// cols: 128x16 tile per block (8 tiles per image), transform along y
template<int SIGNPOS, int REALOUT, int SCALE>
__global__ void __launch_bounds__(256) k_fft_cols(const float2* in, float2* outc, float* outr){
    const float sgn = SIGNPOS ? 1.0f : -1.0f;
    __shared__ float tre[N*17];
    __shared__ float tim_[N*17];
    __shared__ float zre[8*16*17];
    __shared__ float zim[8*16*17];
    int t = threadIdx.x;
    int img = blockIdx.x >> 3; int x0 = (blockIdx.x & 7)*16;
    const float2* src = in + (size_t)img*N*N + x0;
    #pragma unroll
    for(int j=0;j<8;j++){
        int idx = t + 256*j; int y = idx>>4, xc = idx&15;
        float2 v = src[y*N + xc];
        tre[y*17+xc]=v.x; tim_[y*17+xc]=v.y;
    }
    float t16c[16], t16s[16];
    #pragma unroll
    for(int j=0;j<16;j++){ float s,c; sincosf(sgn*(TWO_PI_F/16.f)*(float)j, &s,&c); t16c[j]=c; t16s[j]=s; }
    __syncthreads();

    int xc = t&15, u = t>>4, b = u&7, h = u>>3;
    float xr[16], xi[16];
    #pragma unroll
    for(int a=0;a<16;a++){
        int y = 8*a + b;
        float vr = tre[y*17+xc];
        float vi = tim_[y*17+xc];
        if(h && (a&1)){ vr = -vr; vi = -vi; }
        xr[a]=vr; xi[a]=vi;
    }
    #pragma unroll
    for(int cc=0; cc<8; cc++){
        float yr=0.f, yi=0.f;
        #pragma unroll
        for(int a=0;a<16;a++){
            int j = (a*cc)&15;
            yr += xr[a]*t16c[j] - xi[a]*t16s[j];
            yi += xr[a]*t16s[j] + xi[a]*t16c[j];
        }
        int c = 8*h + cc;
        float s,co; sincosf(sgn*(TWO_PI_F/128.f)*(float)(b*c), &s,&co);
        zre[(b*16 + c)*17 + xc] = yr*co - yi*s;
        zim[(b*16 + c)*17 + xc] = yr*s + yi*co;
    }
    __syncthreads();

    float t8c[8], t8s[8];
    #pragma unroll
    for(int j=0;j<8;j++){ float s,c; sincosf(sgn*(TWO_PI_F/8.f)*(float)j, &s,&c); t8c[j]=c; t8s[j]=s; }
    int c2 = t>>4; int x2 = t&15;
    float zr_[8], zi_[8];
    #pragma unroll
    for(int bb=0;bb<8;bb++){ zr_[bb]=zre[(bb*16 + c2)*17 + x2]; zi_[bb]=zim[(bb*16 + c2)*17 + x2]; }
    #pragma unroll
    for(int d=0; d<8; d++){
        float Xr=0.f, Xi=0.f;
        #pragma unroll
        for(int bb=0;bb<8;bb++){
            int j=(bb*d)&7;
            Xr += zr_[bb]*t8c[j] - zi_[bb]*t8s[j];
            Xi += zr_[bb]*t8s[j] + zi_[bb]*t8c[j];
        }
        int ky = c2 + 16*d;
        if(REALOUT){
            outr[(size_t)img*N*N + ky*N + x0 + x2] = Xr * (SCALE ? (1.f/128.f) : 1.f);
        } else {
            if(SCALE){ Xr *= (1.f/128.f); Xi *= (1.f/128.f); }
            outc[(size_t)img*N*N + ky*N + x0 + x2] = make_float2(Xr, Xi);
        }
    }
}

// per frequency point: Hsum[ik] = sum_p A1T[o][ik,p]*W2T[x][ik,p]; res1[b,k] = sum_i alpha[b,i]*Hsum[i,k]
__global__ void __launch_bounds__(256) k_res1(const float2* alpha, const float2* A1T,
                                              const float2* W2T, float2* res1){
    __shared__ float2 aval[B*CI];   // 256
    __shared__ float2 hs[IK];       // 1024
    int t = threadIdx.x;
    int f = blockIdx.x;
    int o = f >> 7; int xx = f & (N-1);
    aval[t] = alpha[(size_t)t*(N*N) + o*N + xx];
    const float2* a1 = A1T + (size_t)o*IKP;
    const float2* w2 = W2T + (size_t)xx*IKP;
    #pragma unroll
    for(int nn=0;nn<4;nn++){
        int ik = t + 256*nn;
        float2 h = make_float2(0.f,0.f);
        #pragma unroll
        for(int p=0;p<M1;p++){
            h = cmadd(h, a1[ik*M1+p], w2[ik*M1+p]);
        }
        hs[ik] = h;
    }
    __syncthreads();
    int b = t >> 5; int k = t & 31;
    float2 acc = make_float2(0.f,0.f);
    const float2* av = aval + b*CI;
    #pragma unroll
    for(int i=0;i<CI;i++){
        acc = cmadd(acc, av[i], hs[i*CO + k]);
    }
    res1[((size_t)(b*CO + k))*(N*N) + o*N + xx] = acc;
}

// per (b,i,kgroup of KG=8): U[kk][q] = sum_x alpha[b,i,o,x]*A2[ik,q,x] per o (=thread);
// then S[kk][p][q] = sum_o A1[ik,p,o]*U; res2 += wr*S (atomics over i).
__global__ void __launch_bounds__(128) k_S_res2(const float2* alpha, const float2* A2,
                                                const float2* A1T, const float* wrr,
                                                const float* wri, float2* res2){
    __shared__ __align__(16) unsigned char smem_pool[25088];
    float*  tre = (float*)smem_pool;              // [128][17]
    float*  tim = tre + 128*17;                   // [128][17]
    float2* A2c = (float2*)(tim + 128*17);        // [16][40] float2
    float2* red = (float2*)smem_pool;             // [128][21] float2, reused after U-phase

    int t = threadIdx.x;           // o
    int bid = blockIdx.x;          // (b*CI + i)*4 + kg
    int kg = bid & 3;
    int i  = (bid >> 2) & (CI-1);
    int b  = bid >> 7;
    int k0 = kg*KG;
    const float2* asrc = alpha + ((size_t)(b*CI + i))*(N*N);

    float2 U[KG*M2];
    #pragma unroll
    for(int r=0;r<KG*M2;r++) U[r] = make_float2(0.f,0.f);

    for(int cx=0; cx<8; cx++){
        int x0 = cx*16;
        __syncthreads();
        #pragma unroll
        for(int j=0;j<16;j++){
            int l = t + 128*j;
            int ol = l >> 4, xc = l & 15;
            float2 v = asrc[ol*N + x0 + xc];
            tre[ol*17+xc] = v.x;
            tim[ol*17+xc] = v.y;
        }
        #pragma unroll
        for(int s=0;s<5;s++){
            int e = t + 128*s;                    // 640 = 16*40
            int xc = e / 40, r = e - xc*40;
            int kk = r / M2, q = r - kk*M2;
            A2c[xc*40 + r] = A2[((size_t)(i*CO + k0 + kk))*(M2*N) + q*N + x0 + xc];
        }
        __syncthreads();
        #pragma unroll 2
        for(int xc=0; xc<16; xc++){
            float2 av = make_float2(tre[t*17+xc], tim[t*17+xc]);
            const float2* a2row = A2c + xc*40;
            #pragma unroll
            for(int r=0;r<KG*M2;r++) U[r] = cmadd(U[r], av, a2row[r]);
        }
    }
    __syncthreads();

    const float2* A1p = A1T + (size_t)t*IKP + (size_t)(i*CO + k0)*M1;
    #pragma unroll
    for(int kk=0;kk<KG;kk++){
        float2 a1kp[M1];
        #pragma unroll
        for(int p=0;p<M1;p++) a1kp[p] = A1p[kk*M1+p];
        #pragma unroll
        for(int p=0;p<M1;p++){
            #pragma unroll
            for(int q=0;q<M2;q++){
                red[t*21 + p*M2+q] = cmul(a1kp[p], U[kk*M2+q]);
            }
        }
        __syncthreads();
        #pragma unroll
        for(int s=0;s<5;s++){
            int e = t + 128*s;                    // 640 = 32*20
            int r = e / 20, pq = e - r*20;
            float2 acc = red[r*21+pq];
            float2 v1 = red[(r+32)*21+pq];
            float2 v2 = red[(r+64)*21+pq];
            float2 v3 = red[(r+96)*21+pq];
            acc.x += v1.x + v2.x + v3.x;
            acc.y += v1.y + v2.y + v3.y;
            red[r*21+pq] = acc;
        }
        __syncthreads();
        if(t < M1*M2){
            float2 S = make_float2(0.f,0.f);
            for(int r=0;r<32;r++){ S.x += red[r*21+t].x; S.y += red[r*21+t].y; }
            int ik = i*CO + k0 + kk;
            float2 w = make_float2(wrr[ik*(M1*M2)+t], wri[ik*(M1*M2)+t]);
            float2 v = cmul(w, S);
            float2* dst = res2 + (size_t)(b*CO + k0 + kk)*(M1*M2) + t;
            atomicAdd(&dst->x, v.x);
            atomicAdd(&dst->y, v.y);
        }
        __syncthreads();
    }
}

// x2[b,j,y,x] += (1/N^2) * Re( sum_{c,p,q} res2[b,c,p,q]*E1[c,j,p,y]*E2[c,j,q,x] )
__global__ void __launch_bounds__(256) k_x2(const float2* res2, const float2* E1,
                                            const float2* E2, float* out){
    __shared__ float2 Wt[M1][N];
    __shared__ float2 E1s[M1][N];
    int t = threadIdx.x;
    int b = blockIdx.x >> 5; int j = blockIdx.x & 31;
    int xx = t & (N-1); int hb = t >> 7;
    float acc[64];
    #pragma unroll
    for(int r=0;r<64;r++) acc[r]=0.f;
    for(int c=0;c<CI;c++){
        int ikcj = c*CO + j;
        __syncthreads();
        #pragma unroll
        for(int s=0;s<2;s++){
            int e = t + 256*s;
            int pp = e >> 7; int xi = e & (N-1);
            float2 w = make_float2(0.f,0.f);
            const float2* r2 = res2 + (size_t)(b*CO + c)*(M1*M2) + pp*M2;
            const float2* e2 = E2 + ((size_t)ikcj*M2)*N + xi;
            #pragma unroll
            for(int q=0;q<M2;q++) w = cmadd(w, r2[q], e2[q*N]);
            Wt[pp][xi] = w;
            E1s[pp][xi] = E1[((size_t)ikcj*M1 + pp)*N + xi];
        }
        __syncthreads();
        float2 wreg[M1];
        #pragma unroll
        for(int p=0;p<M1;p++) wreg[p] = Wt[p][xx];
        #pragma unroll
        for(int r=0;r<64;r++){
            int y = 2*r + hb;
            float s = 0.f;
            #pragma unroll
            for(int p=0;p<M1;p++){
                float2 e = E1s[p][y];
                s += e.x*wreg[p].x - e.y*wreg[p].y;
            }
            acc[r] += s;
        }
    }
    const float sc = 1.0f/((float)N*(float)N);
    size_t base = (size_t)(b*CO + j)*(N*N);
    #pragma unroll
    for(int r=0;r<64;r++){
        size_t idx = base + (size_t)(2*r+hb)*N + xx;
        out[idx] += acc[r]*sc;
    }
}

extern "C" void kernel_launch(void* const* d_in, const int* in_sizes, int n_in,
                              void* d_out, int out_size, void* d_ws, size_t ws_size,
                              hipStream_t stream){
    const float* x    = (const float*)d_in[0];
    const float* wp1r = (const float*)d_in[1];
    const float* wp1i = (const float*)d_in[2];
    const float* wp2r = (const float*)d_in[3];
    const float* wp2i = (const float*)d_in[4];
    const float* wrr  = (const float*)d_in[5];
    const float* wri  = (const float*)d_in[6];
    const float* ty   = (const float*)d_in[7];
    const float* tx   = (const float*)d_in[8];
    float* out = (float*)d_out;
    float2* ws = (float2*)d_ws;

    const size_t NCIMG = (size_t)B*CI*N*N;        // 4194304 complexes
    float2* bufA  = ws;
    float2* alpha = bufA  + NCIMG;
    float2* res1  = alpha + NCIMG;
    float2* A1T   = res1  + NCIMG;                // N*IKP
    float2* A2    = A1T   + (size_t)N*IKP;        // IKQ*N
    float2* W2T   = A2    + (size_t)IKQ*N;        // N*IKP
    float2* E1    = W2T   + (size_t)N*IKP;        // IKP*N
    float2* E2    = E1    + (size_t)IKP*N;        // IKQ*N
    float2* res2  = E2    + (size_t)IKQ*N;        // B*CO*M1*M2

    k_A1T<<<(N*IKP)/256, 256, 0, stream>>>(wp1r, wp1i, ty, A1T);
    k_E  <<<(IKP*N)/256, 256, 0, stream>>>(wp1r, wp1i, ty, E1);
    k_A2 <<<(IKQ*N)/256, 256, 0, stream>>>(wp2r, wp2i, tx, A2);
    k_E  <<<(IKQ*N)/256, 256, 0, stream>>>(wp2r, wp2i, tx, E2);
    k_W2T<<<(IKP*N)/256, 256, 0, stream>>>(wrr, wri, A2, W2T);

    // forward fft2: rows (real in) then cols
    k_fft_rows<0,1,0><<<(B*CI*N)/16, 256, 0, stream>>>((const void*)x, bufA);
    k_fft_cols<0,0,0><<<B*CI*8, 256, 0, stream>>>(bufA, alpha, nullptr);

    hipMemsetAsync(res2, 0, (size_t)B*CO*M1*M2*sizeof(float2), stream);
    k_res1<<<N*N, 256, 0, stream>>>(alpha, A1T, W2T, res1);
    k_S_res2<<<B*CI*(CO/KG), 128, 0, stream>>>(alpha, A2, A1T, wrr, wri, res2);

    // inverse fft2: rows (1/N) then cols (real out, 1/N)
    k_fft_rows<1,0,1><<<(B*CO*N)/16, 256, 0, stream>>>((const void*)res1, bufA);
    k_fft_cols<1,1,1><<<B*CO*8, 256, 0, stream>>>(bufA, nullptr, out);
    k_x2<<<B*CO, 256, 0, stream>>>(res2, E1, E2, out);
}

// Round 4
// 602.487 us; speedup vs baseline: 1.8474x; 1.1740x over previous
//
#include <hip/hip_runtime.h>
#include <math.h>

#define N 128
#define B 8
#define CI 32
#define CO 32
#define M1 4
#define M2 5
#define IK (CI*CO)       // 1024
#define IKP (IK*M1)      // 4096
#define IKQ (IK*M2)      // 5120
#define TWO_PI_F 6.2831853071795864769f

__device__ __forceinline__ float2 cmul(float2 a, float2 b){
    return make_float2(a.x*b.x - a.y*b.y, a.x*b.y + a.y*b.x);
}
__device__ __forceinline__ float2 cmadd(float2 acc, float2 a, float2 b){
    acc.x += a.x*b.x - a.y*b.y;
    acc.y += a.x*b.y + a.y*b.x;
    return acc;
}

// A1T[o][ik*M1+p] = 1/(i*2pi*f(o) - wp1[ik,p]); freq-major for contiguous per-o slices
__global__ void k_A1T(const float* wr_, const float* wi_, const float* t_, float2* A1T){
    int idx = blockIdx.x*256 + threadIdx.x;      // [0, N*IKP)
    int o   = idx >> 12;                          // /IKP
    int ikp = idx & (IKP-1);
    float d = t_[1]-t_[0];
    float invnd = 1.0f/((float)N*d);
    int kk = (o < N/2) ? o : o - N;
    float lam = TWO_PI_F * (float)kk * invnd;
    float dr = -wr_[ikp];
    float di = lam - wi_[ikp];
    float inv = 1.0f/(dr*dr + di*di);
    A1T[idx] = make_float2(dr*inv, -di*inv);
}

// A2[ikq][x] natural layout
__global__ void k_A2(const float* wr_, const float* wi_, const float* t_, float2* A2){
    int idx = blockIdx.x*256 + threadIdx.x;      // [0, IKQ*N)
    int ikq = idx >> 7; int xx = idx & (N-1);
    float d = t_[1]-t_[0];
    float invnd = 1.0f/((float)N*d);
    int kk = (xx < N/2) ? xx : xx - N;
    float lam = TWO_PI_F * (float)kk * invnd;
    float dr = -wr_[ikq];
    float di = lam - wi_[ikq];
    float inv = 1.0f/(dr*dr + di*di);
    A2[idx] = make_float2(dr*inv, -di*inv);
}

// E[ikp][y] = exp(wp[ikp] * t[y])
__global__ void k_E(const float* wr_, const float* wi_, const float* t_, float2* E){
    int idx = blockIdx.x*256 + threadIdx.x;
    int ikp = idx >> 7; int y = idx & (N-1);
    float t = t_[y];
    float m = expf(wr_[ikp]*t);
    float s, c; sincosf(wi_[ikp]*t, &s, &c);
    E[idx] = make_float2(m*c, m*s);
}

// W2T[x][ik*M1+p] = sum_q wr[ik,p,q] * A2[ik,q,x]
__global__ void k_W2T(const float* wrr, const float* wri, const float2* A2, float2* W2T){
    int idx = blockIdx.x*256 + threadIdx.x;      // [0, IKP*N)
    int ikp = idx >> 7; int xx = idx & (N-1);
    int ik = ikp >> 2; int p = ikp & 3;
    float2 acc = make_float2(0.f,0.f);
    const float* wr0 = wrr + ik*(M1*M2) + p*M2;
    const float* wi0 = wri + ik*(M1*M2) + p*M2;
    const float2* a2 = A2 + (size_t)ik*(M2*N) + xx;
    #pragma unroll
    for(int q=0;q<M2;q++){
        float2 w = make_float2(wr0[q], wi0[q]);
        acc = cmadd(acc, w, a2[q*N]);
    }
    W2T[(size_t)xx*IKP + ikp] = acc;
}

// ---------- four-step FFT, 128 = 16 x 8 ----------
template<int SIGNPOS, int REALIN, int SCALE>
__global__ void __launch_bounds__(256) k_fft_rows(const void* in_, float2* out){
    const float sgn = SIGNPOS ? 1.0f : -1.0f;
    __shared__ float tre[16*132];
    __shared__ float tim_[16*132];
    __shared__ float zre[16*136];
    __shared__ float zim[16*136];
    int t = threadIdx.x;
    size_t row0 = (size_t)blockIdx.x * 16;

    if(REALIN){
        const float* src = (const float*)in_ + row0*N;
        #pragma unroll
        for(int j=0;j<8;j++){
            int idx = t + 256*j; int r = idx>>7, cl = idx&127;
            tre[r*132+cl] = src[idx];
        }
    } else {
        const float2* src = (const float2*)in_ + row0*N;
        #pragma unroll
        for(int j=0;j<8;j++){
            int idx = t + 256*j; int r = idx>>7, cl = idx&127;
            float2 v = src[idx];
            tre[r*132+cl] = v.x; tim_[r*132+cl] = v.y;
        }
    }
    float t16c[16], t16s[16];
    #pragma unroll
    for(int j=0;j<16;j++){ float s,c; sincosf(sgn*(TWO_PI_F/16.f)*(float)j, &s,&c); t16c[j]=c; t16s[j]=s; }
    __syncthreads();

    int r = t>>4, u = t&15, b = u&7, h = u>>3;
    float xr[16], xi[16];
    #pragma unroll
    for(int a=0;a<16;a++){
        float vr = tre[r*132 + 8*a + b];
        float vi = REALIN ? 0.f : tim_[r*132 + 8*a + b];
        if(h && (a&1)){ vr = -vr; vi = -vi; }
        xr[a]=vr; xi[a]=vi;
    }
    #pragma unroll
    for(int cc=0; cc<8; cc++){
        float yr=0.f, yi=0.f;
        #pragma unroll
        for(int a=0;a<16;a++){
            int j = (a*cc)&15;
            if(REALIN){
                yr += xr[a]*t16c[j];
                yi += xr[a]*t16s[j];
            } else {
                yr += xr[a]*t16c[j] - xi[a]*t16s[j];
                yi += xr[a]*t16s[j] + xi[a]*t16c[j];
            }
        }
        int c = 8*h + cc;
        float s,co; sincosf(sgn*(TWO_PI_F/128.f)*(float)(b*c), &s,&co);
        zre[r*136 + b*17 + c] = yr*co - yi*s;
        zim[r*136 + b*17 + c] = yr*s + yi*co;
    }
    __syncthreads();

    float t8c[8], t8s[8];
    #pragma unroll
    for(int j=0;j<8;j++){ float s,c; sincosf(sgn*(TWO_PI_F/8.f)*(float)j, &s,&c); t8c[j]=c; t8s[j]=s; }
    int r2 = t>>4, c2 = t&15;
    float zr_[8], zi_[8];
    #pragma unroll
    for(int bb=0;bb<8;bb++){ zr_[bb]=zre[r2*136 + bb*17 + c2]; zi_[bb]=zim[r2*136 + bb*17 + c2]; }
    float2* dst = out + (row0 + r2)*N;
    #pragma unroll
    for(int d=0; d<8; d++){
        float Xr=0.f, Xi=0.f;
        #pragma unroll
        for(int bb=0;bb<8;bb++){
            int j=(bb*d)&7;
            Xr += zr_[bb]*t8c[j] - zi_[bb]*t8s[j];
            Xi += zr_[bb]*t8s[j] + zi_[bb]*t8c[j];
        }
        if(SCALE){ Xr *= (1.f/128.f); Xi *= (1.f/128.f); }
        dst[c2 + 16*d] = make_float2(Xr, Xi);
    }
}

template<int SIGNPOS, int REALOUT, int SCALE>
__global__ void __launch_bounds__(256) k_fft_cols(const float2* in, float2* outc, float* outr){
    const float sgn = SIGNPOS ? 1.0f : -1.0f;
    __shared__ float tre[N*17];
    __shared__ float tim_[N*17];
    __shared__ float zre[8*16*17];
    __shared__ float zim[8*16*17];
    int t = threadIdx.x;
    int img = blockIdx.x >> 3; int x0 = (blockIdx.x & 7)*16;
    const float2* src = in + (size_t)img*N*N + x0;
    #pragma unroll
    for(int j=0;j<8;j++){
        int idx = t + 256*j; int y = idx>>4, xc = idx&15;
        float2 v = src[y*N + xc];
        tre[y*17+xc]=v.x; tim_[y*17+xc]=v.y;
    }
    float t16c[16], t16s[16];
    #pragma unroll
    for(int j=0;j<16;j++){ float s,c; sincosf(sgn*(TWO_PI_F/16.f)*(float)j, &s,&c); t16c[j]=c; t16s[j]=s; }
    __syncthreads();

    int xc = t&15, u = t>>4, b = u&7, h = u>>3;
    float xr[16], xi[16];
    #pragma unroll
    for(int a=0;a<16;a++){
        int y = 8*a + b;
        float vr = tre[y*17+xc];
        float vi = tim_[y*17+xc];
        if(h && (a&1)){ vr = -vr; vi = -vi; }
        xr[a]=vr; xi[a]=vi;
    }
    #pragma unroll
    for(int cc=0; cc<8; cc++){
        float yr=0.f, yi=0.f;
        #pragma unroll
        for(int a=0;a<16;a++){
            int j = (a*cc)&15;
            yr += xr[a]*t16c[j] - xi[a]*t16s[j];
            yi += xr[a]*t16s[j] + xi[a]*t16c[j];
        }
        int c = 8*h + cc;
        float s,co; sincosf(sgn*(TWO_PI_F/128.f)*(float)(b*c), &s,&co);
        zre[(b*16 + c)*17 + xc] = yr*co - yi*s;
        zim[(b*16 + c)*17 + xc] = yr*s + yi*co;
    }
    __syncthreads();

    float t8c[8], t8s[8];
    #pragma unroll
    for(int j=0;j<8;j++){ float s,c; sincosf(sgn*(TWO_PI_F/8.f)*(float)j, &s,&c); t8c[j]=c; t8s[j]=s; }
    int c2 = t>>4; int x2 = t&15;
    float zr_[8], zi_[8];
    #pragma unroll
    for(int bb=0;bb<8;bb++){ zr_[bb]=zre[(bb*16 + c2)*17 + x2]; zi_[bb]=zim[(bb*16 + c2)*17 + x2]; }
    #pragma unroll
    for(int d=0; d<8; d++){
        float Xr=0.f, Xi=0.f;
        #pragma unroll
        for(int bb=0;bb<8;bb++){
            int j=(bb*d)&7;
            Xr += zr_[bb]*t8c[j] - zi_[bb]*t8s[j];
            Xi += zr_[bb]*t8s[j] + zi_[bb]*t8c[j];
        }
        int ky = c2 + 16*d;
        if(REALOUT){
            outr[(size_t)img*N*N + ky*N + x0 + x2] = Xr * (SCALE ? (1.f/128.f) : 1.f);
        } else {
            if(SCALE){ Xr *= (1.f/128.f); Xi *= (1.f/128.f); }
            outc[(size_t)img*N*N + ky*N + x0 + x2] = make_float2(Xr, Xi);
        }
    }
}

// per frequency point: Hsum[ik] = sum_p A1T[o][ik,p]*W2T[x][ik,p]; res1[b,k] = sum_i alpha[b,i]*Hsum[i,k]
__global__ void __launch_bounds__(256) k_res1(const float2* alpha, const float2* A1T,
                                              const float2* W2T, float2* res1){
    __shared__ float2 aval[B*CI];   // 256
    __shared__ float2 hs[IK];       // 1024
    int t = threadIdx.x;
    int f = blockIdx.x;
    int o = f >> 7; int xx = f & (N-1);
    aval[t] = alpha[(size_t)t*(N*N) + o*N + xx];
    const float2* a1 = A1T + (size_t)o*IKP;
    const float2* w2 = W2T + (size_t)xx*IKP;
    #pragma unroll
    for(int nn=0;nn<4;nn++){
        int ik = t + 256*nn;
        float2 h = make_float2(0.f,0.f);
        #pragma unroll
        for(int p=0;p<M1;p++){
            h = cmadd(h, a1[ik*M1+p], w2[ik*M1+p]);
        }
        hs[ik] = h;
    }
    __syncthreads();
    int b = t >> 5; int k = t & 31;
    float2 acc = make_float2(0.f,0.f);
    const float2* av = aval + b*CI;
    #pragma unroll
    for(int i=0;i<CI;i++){
        acc = cmadd(acc, av[i], hs[i*CO + k]);
    }
    res1[((size_t)(b*CO + k))*(N*N) + o*N + xx] = acc;
}

// per (b, i, k-quad): 128 threads = 32 o-lanes x 4 k-groups.
// Thread (ol, rg): o in {ol, ol+32, ol+64, ol+96}, k = kquad*4+rg, q=0..4.
// U[oi][q] = sum_x alpha[b,i,o,x]*A2[ik,q,x]; S[p][q] = sum_o A1[ik,p,o]*U (in-reg +
// 32-lane butterfly); res2 += wr*S (atomics over i).
__global__ void __launch_bounds__(128) k_S_res2(const float2* alpha, const float2* A2,
                                                const float2* A1T, const float* wrr,
                                                const float* wri, float2* res2){
    __shared__ float2 tile[128*17];   // alpha chunk [o][xc], stride 17 (2-way banks: free)
    __shared__ float2 A2c[16*20];     // [xc][r], r = kk*5+q
    int t = threadIdx.x;
    int ol = t & 31, rg = t >> 5;
    int bid = blockIdx.x;             // (b*CI + i)*8 + kquad
    int kq = bid & 7;
    int i  = (bid >> 3) & (CI-1);
    int b  = bid >> 8;
    int k0 = kq*4;
    int k  = k0 + rg;
    int ik = i*CO + k;
    const float2* asrc = alpha + ((size_t)(b*CI + i))*(N*N);

    float2 U[4][5];
    #pragma unroll
    for(int oi=0;oi<4;oi++)
        #pragma unroll
        for(int q=0;q<5;q++) U[oi][q] = make_float2(0.f,0.f);

    for(int cx=0; cx<8; cx++){
        int x0 = cx*16;
        __syncthreads();
        #pragma unroll
        for(int j=0;j<16;j++){
            int l = t + 128*j;
            int orow = l >> 4, xc = l & 15;
            tile[orow*17+xc] = asrc[orow*N + x0 + xc];
        }
        #pragma unroll
        for(int s=0;s<3;s++){
            int e = t + 128*s;
            if(e < 320){
                int xc = e / 20, r = e - xc*20;
                int kk = r / 5, q = r - kk*5;
                A2c[xc*20 + r] = A2[((size_t)(i*CO + k0 + kk))*(M2*N) + q*N + x0 + xc];
            }
        }
        __syncthreads();
        #pragma unroll 4
        for(int xc=0; xc<16; xc++){
            float2 a2v[5];
            const float2* a2row = A2c + xc*20 + rg*5;
            #pragma unroll
            for(int q=0;q<5;q++) a2v[q] = a2row[q];
            #pragma unroll
            for(int oi=0;oi<4;oi++){
                float2 av = tile[(ol+32*oi)*17 + xc];
                #pragma unroll
                for(int q=0;q<5;q++) U[oi][q] = cmadd(U[oi][q], av, a2v[q]);
            }
        }
    }

    // S-phase: in-register over this thread's 4 o's
    float2 S[4][5];
    #pragma unroll
    for(int p=0;p<4;p++)
        #pragma unroll
        for(int q=0;q<5;q++) S[p][q] = make_float2(0.f,0.f);
    #pragma unroll
    for(int oi=0;oi<4;oi++){
        int o = ol + 32*oi;
        const float2* a1 = A1T + (size_t)o*IKP + (size_t)ik*M1;
        float2 a1v[4];
        #pragma unroll
        for(int p=0;p<4;p++) a1v[p] = a1[p];
        #pragma unroll
        for(int p=0;p<4;p++)
            #pragma unroll
            for(int q=0;q<5;q++) S[p][q] = cmadd(S[p][q], a1v[p], U[oi][q]);
    }
    // butterfly over the 32 o-lanes (masks <32 stay within each rg pair's half-wave)
    #pragma unroll
    for(int m=1;m<32;m<<=1){
        #pragma unroll
        for(int p=0;p<4;p++)
            #pragma unroll
            for(int q=0;q<5;q++){
                S[p][q].x += __shfl_xor(S[p][q].x, m);
                S[p][q].y += __shfl_xor(S[p][q].y, m);
            }
    }
    if(ol==0){
        const float* wr0 = wrr + ik*(M1*M2);
        const float* wi0 = wri + ik*(M1*M2);
        float2* dst = res2 + (size_t)(b*CO + k)*(M1*M2);
        #pragma unroll
        for(int p=0;p<4;p++)
            #pragma unroll
            for(int q=0;q<5;q++){
                float2 w = make_float2(wr0[p*5+q], wi0[p*5+q]);
                float2 v = cmul(w, S[p][q]);
                atomicAdd(&dst[p*5+q].x, v.x);
                atomicAdd(&dst[p*5+q].y, v.y);
            }
    }
}

// x2[b,j,y,x] += (1/N^2) * Re( sum_{c,p,q} res2[b,c,p,q]*E1[c,j,p,y]*E2[c,j,q,x] )
__global__ void __launch_bounds__(256) k_x2(const float2* res2, const float2* E1,
                                            const float2* E2, float* out){
    __shared__ float2 Wt[M1][N];
    __shared__ float2 E1s[M1][N];
    int t = threadIdx.x;
    int b = blockIdx.x >> 5; int j = blockIdx.x & 31;
    int xx = t & (N-1); int hb = t >> 7;
    float acc[64];
    #pragma unroll
    for(int r=0;r<64;r++) acc[r]=0.f;
    for(int c=0;c<CI;c++){
        int ikcj = c*CO + j;
        __syncthreads();
        #pragma unroll
        for(int s=0;s<2;s++){
            int e = t + 256*s;
            int pp = e >> 7; int xi = e & (N-1);
            float2 w = make_float2(0.f,0.f);
            const float2* r2 = res2 + (size_t)(b*CO + c)*(M1*M2) + pp*M2;
            const float2* e2 = E2 + ((size_t)ikcj*M2)*N + xi;
            #pragma unroll
            for(int q=0;q<M2;q++) w = cmadd(w, r2[q], e2[q*N]);
            Wt[pp][xi] = w;
            E1s[pp][xi] = E1[((size_t)ikcj*M1 + pp)*N + xi];
        }
        __syncthreads();
        float2 wreg[M1];
        #pragma unroll
        for(int p=0;p<M1;p++) wreg[p] = Wt[p][xx];
        #pragma unroll
        for(int r=0;r<64;r++){
            int y = 2*r + hb;
            float s = 0.f;
            #pragma unroll
            for(int p=0;p<M1;p++){
                float2 e = E1s[p][y];
                s += e.x*wreg[p].x - e.y*wreg[p].y;
            }
            acc[r] += s;
        }
    }
    const float sc = 1.0f/((float)N*(float)N);
    size_t base = (size_t)(b*CO + j)*(N*N);
    #pragma unroll
    for(int r=0;r<64;r++){
        size_t idx = base + (size_t)(2*r+hb)*N + xx;
        out[idx] += acc[r]*sc;
    }
}

extern "C" void kernel_launch(void* const* d_in, const int* in_sizes, int n_in,
                              void* d_out, int out_size, void* d_ws, size_t ws_size,
                              hipStream_t stream){
    const float* x    = (const float*)d_in[0];
    const float* wp1r = (const float*)d_in[1];
    const float* wp1i = (const float*)d_in[2];
    const float* wp2r = (const float*)d_in[3];
    const float* wp2i = (const float*)d_in[4];
    const float* wrr  = (const float*)d_in[5];
    const float* wri  = (const float*)d_in[6];
    const float* ty   = (const float*)d_in[7];
    const float* tx   = (const float*)d_in[8];
    float* out = (float*)d_out;
    float2* ws = (float2*)d_ws;

    const size_t NCIMG = (size_t)B*CI*N*N;        // 4194304 complexes
    float2* bufA  = ws;
    float2* alpha = bufA  + NCIMG;
    float2* res1  = alpha + NCIMG;
    float2* A1T   = res1  + NCIMG;                // N*IKP
    float2* A2    = A1T   + (size_t)N*IKP;        // IKQ*N
    float2* W2T   = A2    + (size_t)IKQ*N;        // N*IKP
    float2* E1    = W2T   + (size_t)N*IKP;        // IKP*N
    float2* E2    = E1    + (size_t)IKP*N;        // IKQ*N
    float2* res2  = E2    + (size_t)IKQ*N;        // B*CO*M1*M2

    k_A1T<<<(N*IKP)/256, 256, 0, stream>>>(wp1r, wp1i, ty, A1T);
    k_E  <<<(IKP*N)/256, 256, 0, stream>>>(wp1r, wp1i, ty, E1);
    k_A2 <<<(IKQ*N)/256, 256, 0, stream>>>(wp2r, wp2i, tx, A2);
    k_E  <<<(IKQ*N)/256, 256, 0, stream>>>(wp2r, wp2i, tx, E2);
    k_W2T<<<(IKP*N)/256, 256, 0, stream>>>(wrr, wri, A2, W2T);

    // forward fft2: rows (real in) then cols
    k_fft_rows<0,1,0><<<(B*CI*N)/16, 256, 0, stream>>>((const void*)x, bufA);
    k_fft_cols<0,0,0><<<B*CI*8, 256, 0, stream>>>(bufA, alpha, nullptr);

    hipMemsetAsync(res2, 0, (size_t)B*CO*M1*M2*sizeof(float2), stream);
    k_res1<<<N*N, 256, 0, stream>>>(alpha, A1T, W2T, res1);
    k_S_res2<<<B*CI*8, 128, 0, stream>>>(alpha, A2, A1T, wrr, wri, res2);

    // inverse fft2: rows (1/N) then cols (real out, 1/N)
    k_fft_rows<1,0,1><<<(B*CO*N)/16, 256, 0, stream>>>((const void*)res1, bufA);
    k_fft_cols<1,1,1><<<B*CO*8, 256, 0, stream>>>(bufA, nullptr, out);
    k_x2<<<B*CO, 256, 0, stream>>>(res2, E1, E2, out);
}

// Round 5
// 602.284 us; speedup vs baseline: 1.8481x; 1.0003x over previous
//
#include <hip/hip_runtime.h>
#include <math.h>

#define N 128
#define B 8
#define CI 32
#define CO 32
#define M1 4
#define M2 5
#define IK (CI*CO)       // 1024
#define IKP (IK*M1)      // 4096
#define IKQ (IK*M2)      // 5120
#define TWO_PI_F 6.2831853071795864769f

__device__ __forceinline__ float2 cmul(float2 a, float2 b){
    return make_float2(a.x*b.x - a.y*b.y, a.x*b.y + a.y*b.x);
}
__device__ __forceinline__ float2 cmadd(float2 acc, float2 a, float2 b){
    acc.x += a.x*b.x - a.y*b.y;
    acc.y += a.x*b.y + a.y*b.x;
    return acc;
}

// A1T[o][ik*M1+p] = 1/(i*2pi*f(o) - wp1[ik,p]); freq-major for contiguous per-o slices
__global__ void k_A1T(const float* wr_, const float* wi_, const float* t_, float2* A1T){
    int idx = blockIdx.x*256 + threadIdx.x;      // [0, N*IKP)
    int o   = idx >> 12;                          // /IKP
    int ikp = idx & (IKP-1);
    float d = t_[1]-t_[0];
    float invnd = 1.0f/((float)N*d);
    int kk = (o < N/2) ? o : o - N;
    float lam = TWO_PI_F * (float)kk * invnd;
    float dr = -wr_[ikp];
    float di = lam - wi_[ikp];
    float inv = 1.0f/(dr*dr + di*di);
    A1T[idx] = make_float2(dr*inv, -di*inv);
}

// A2[ikq][x] natural layout
__global__ void k_A2(const float* wr_, const float* wi_, const float* t_, float2* A2){
    int idx = blockIdx.x*256 + threadIdx.x;      // [0, IKQ*N)
    int ikq = idx >> 7; int xx = idx & (N-1);
    float d = t_[1]-t_[0];
    float invnd = 1.0f/((float)N*d);
    int kk = (xx < N/2) ? xx : xx - N;
    float lam = TWO_PI_F * (float)kk * invnd;
    float dr = -wr_[ikq];
    float di = lam - wi_[ikq];
    float inv = 1.0f/(dr*dr + di*di);
    A2[idx] = make_float2(dr*inv, -di*inv);
}

// E[ikp][y] = exp(wp[ikp] * t[y])
__global__ void k_E(const float* wr_, const float* wi_, const float* t_, float2* E){
    int idx = blockIdx.x*256 + threadIdx.x;
    int ikp = idx >> 7; int y = idx & (N-1);
    float t = t_[y];
    float m = expf(wr_[ikp]*t);
    float s, c; sincosf(wi_[ikp]*t, &s, &c);
    E[idx] = make_float2(m*c, m*s);
}

// W2T[x][ik*M1+p] = sum_q wr[ik,p,q] * A2[ik,q,x]
__global__ void k_W2T(const float* wrr, const float* wri, const float2* A2, float2* W2T){
    int idx = blockIdx.x*256 + threadIdx.x;      // [0, IKP*N)
    int ikp = idx >> 7; int xx = idx & (N-1);
    int ik = ikp >> 2; int p = ikp & 3;
    float2 acc = make_float2(0.f,0.f);
    const float* wr0 = wrr + ik*(M1*M2) + p*M2;
    const float* wi0 = wri + ik*(M1*M2) + p*M2;
    const float2* a2 = A2 + (size_t)ik*(M2*N) + xx;
    #pragma unroll
    for(int q=0;q<M2;q++){
        float2 w = make_float2(wr0[q], wi0[q]);
        acc = cmadd(acc, w, a2[q*N]);
    }
    W2T[(size_t)xx*IKP + ikp] = acc;
}

// ---------- four-step FFT, 128 = 16 x 8 ----------
template<int SIGNPOS, int REALIN, int SCALE>
__global__ void __launch_bounds__(256) k_fft_rows(const void* in_, float2* out){
    const float sgn = SIGNPOS ? 1.0f : -1.0f;
    __shared__ float tre[16*132];
    __shared__ float tim_[16*132];
    __shared__ float zre[16*136];
    __shared__ float zim[16*136];
    int t = threadIdx.x;
    size_t row0 = (size_t)blockIdx.x * 16;

    if(REALIN){
        const float* src = (const float*)in_ + row0*N;
        #pragma unroll
        for(int j=0;j<8;j++){
            int idx = t + 256*j; int r = idx>>7, cl = idx&127;
            tre[r*132+cl] = src[idx];
        }
    } else {
        const float2* src = (const float2*)in_ + row0*N;
        #pragma unroll
        for(int j=0;j<8;j++){
            int idx = t + 256*j; int r = idx>>7, cl = idx&127;
            float2 v = src[idx];
            tre[r*132+cl] = v.x; tim_[r*132+cl] = v.y;
        }
    }
    float t16c[16], t16s[16];
    #pragma unroll
    for(int j=0;j<16;j++){ float s,c; sincosf(sgn*(TWO_PI_F/16.f)*(float)j, &s,&c); t16c[j]=c; t16s[j]=s; }
    __syncthreads();

    int r = t>>4, u = t&15, b = u&7, h = u>>3;
    float xr[16], xi[16];
    #pragma unroll
    for(int a=0;a<16;a++){
        float vr = tre[r*132 + 8*a + b];
        float vi = REALIN ? 0.f : tim_[r*132 + 8*a + b];
        if(h && (a&1)){ vr = -vr; vi = -vi; }
        xr[a]=vr; xi[a]=vi;
    }
    #pragma unroll
    for(int cc=0; cc<8; cc++){
        float yr=0.f, yi=0.f;
        #pragma unroll
        for(int a=0;a<16;a++){
            int j = (a*cc)&15;
            if(REALIN){
                yr += xr[a]*t16c[j];
                yi += xr[a]*t16s[j];
            } else {
                yr += xr[a]*t16c[j] - xi[a]*t16s[j];
                yi += xr[a]*t16s[j] + xi[a]*t16c[j];
            }
        }
        int c = 8*h + cc;
        float s,co; sincosf(sgn*(TWO_PI_F/128.f)*(float)(b*c), &s,&co);
        zre[r*136 + b*17 + c] = yr*co - yi*s;
        zim[r*136 + b*17 + c] = yr*s + yi*co;
    }
    __syncthreads();

    float t8c[8], t8s[8];
    #pragma unroll
    for(int j=0;j<8;j++){ float s,c; sincosf(sgn*(TWO_PI_F/8.f)*(float)j, &s,&c); t8c[j]=c; t8s[j]=s; }
    int r2 = t>>4, c2 = t&15;
    float zr_[8], zi_[8];
    #pragma unroll
    for(int bb=0;bb<8;bb++){ zr_[bb]=zre[r2*136 + bb*17 + c2]; zi_[bb]=zim[r2*136 + bb*17 + c2]; }
    float2* dst = out + (row0 + r2)*N;
    #pragma unroll
    for(int d=0; d<8; d++){
        float Xr=0.f, Xi=0.f;
        #pragma unroll
        for(int bb=0;bb<8;bb++){
            int j=(bb*d)&7;
            Xr += zr_[bb]*t8c[j] - zi_[bb]*t8s[j];
            Xi += zr_[bb]*t8s[j] + zi_[bb]*t8c[j];
        }
        if(SCALE){ Xr *= (1.f/128.f); Xi *= (1.f/128.f); }
        dst[c2 + 16*d] = make_float2(Xr, Xi);
    }
}

template<int SIGNPOS, int REALOUT, int SCALE>
__global__ void __launch_bounds__(256) k_fft_cols(const float2* in, float2* outc, float* outr){
    const float sgn = SIGNPOS ? 1.0f : -1.0f;
    __shared__ float tre[N*17];
    __shared__ float tim_[N*17];
    __shared__ float zre[8*16*17];
    __shared__ float zim[8*16*17];
    int t = threadIdx.x;
    int img = blockIdx.x >> 3; int x0 = (blockIdx.x & 7)*16;
    const float2* src = in + (size_t)img*N*N + x0;
    #pragma unroll
    for(int j=0;j<8;j++){
        int idx = t + 256*j; int y = idx>>4, xc = idx&15;
        float2 v = src[y*N + xc];
        tre[y*17+xc]=v.x; tim_[y*17+xc]=v.y;
    }
    float t16c[16], t16s[16];
    #pragma unroll
    for(int j=0;j<16;j++){ float s,c; sincosf(sgn*(TWO_PI_F/16.f)*(float)j, &s,&c); t16c[j]=c; t16s[j]=s; }
    __syncthreads();

    int xc = t&15, u = t>>4, b = u&7, h = u>>3;
    float xr[16], xi[16];
    #pragma unroll
    for(int a=0;a<16;a++){
        int y = 8*a + b;
        float vr = tre[y*17+xc];
        float vi = tim_[y*17+xc];
        if(h && (a&1)){ vr = -vr; vi = -vi; }
        xr[a]=vr; xi[a]=vi;
    }
    #pragma unroll
    for(int cc=0; cc<8; cc++){
        float yr=0.f, yi=0.f;
        #pragma unroll
        for(int a=0;a<16;a++){
            int j = (a*cc)&15;
            yr += xr[a]*t16c[j] - xi[a]*t16s[j];
            yi += xr[a]*t16s[j] + xi[a]*t16c[j];
        }
        int c = 8*h + cc;
        float s,co; sincosf(sgn*(TWO_PI_F/128.f)*(float)(b*c), &s,&co);
        zre[(b*16 + c)*17 + xc] = yr*co - yi*s;
        zim[(b*16 + c)*17 + xc] = yr*s + yi*co;
    }
    __syncthreads();

    float t8c[8], t8s[8];
    #pragma unroll
    for(int j=0;j<8;j++){ float s,c; sincosf(sgn*(TWO_PI_F/8.f)*(float)j, &s,&c); t8c[j]=c; t8s[j]=s; }
    int c2 = t>>4; int x2 = t&15;
    float zr_[8], zi_[8];
    #pragma unroll
    for(int bb=0;bb<8;bb++){ zr_[bb]=zre[(bb*16 + c2)*17 + x2]; zi_[bb]=zim[(bb*16 + c2)*17 + x2]; }
    #pragma unroll
    for(int d=0; d<8; d++){
        float Xr=0.f, Xi=0.f;
        #pragma unroll
        for(int bb=0;bb<8;bb++){
            int j=(bb*d)&7;
            Xr += zr_[bb]*t8c[j] - zi_[bb]*t8s[j];
            Xi += zr_[bb]*t8s[j] + zi_[bb]*t8c[j];
        }
        int ky = c2 + 16*d;
        if(REALOUT){
            outr[(size_t)img*N*N + ky*N + x0 + x2] = Xr * (SCALE ? (1.f/128.f) : 1.f);
        } else {
            if(SCALE){ Xr *= (1.f/128.f); Xi *= (1.f/128.f); }
            outc[(size_t)img*N*N + ky*N + x0 + x2] = make_float2(Xr, Xi);
        }
    }
}

// per frequency point: Hsum[ik] = sum_p A1T[o][ik,p]*W2T[x][ik,p]; res1[b,k] = sum_i alpha[b,i]*Hsum[i,k]
__global__ void __launch_bounds__(256) k_res1(const float2* alpha, const float2* A1T,
                                              const float2* W2T, float2* res1){
    __shared__ float2 aval[B*CI];   // 256
    __shared__ float2 hs[IK];       // 1024
    int t = threadIdx.x;
    int f = blockIdx.x;
    int o = f >> 7; int xx = f & (N-1);
    aval[t] = alpha[(size_t)t*(N*N) + o*N + xx];
    const float2* a1 = A1T + (size_t)o*IKP;
    const float2* w2 = W2T + (size_t)xx*IKP;
    #pragma unroll
    for(int nn=0;nn<4;nn++){
        int ik = t + 256*nn;
        float2 h = make_float2(0.f,0.f);
        #pragma unroll
        for(int p=0;p<M1;p++){
            h = cmadd(h, a1[ik*M1+p], w2[ik*M1+p]);
        }
        hs[ik] = h;
    }
    __syncthreads();
    int b = t >> 5; int k = t & 31;
    float2 acc = make_float2(0.f,0.f);
    const float2* av = aval + b*CI;
    #pragma unroll
    for(int i=0;i<CI;i++){
        acc = cmadd(acc, av[i], hs[i*CO + k]);
    }
    res1[((size_t)(b*CO + k))*(N*N) + o*N + xx] = acc;
}

// per (b, i, k-octet): 128 threads = 32 o-lanes x 4 rg.
// Thread (ol, rg): o in {ol+32*oi}, k in {k0+rg, k0+rg+4}.
// Software-pipelined staging: next chunk prefetched into regs before barrier.
__global__ void __launch_bounds__(128) k_S_res2(const float2* alpha, const float2* A2,
                                                const float2* A1T, const float* wrr,
                                                const float* wri, float2* res2){
    __shared__ float2 tile[128*17];   // alpha chunk [o][xc], stride 17
    __shared__ float2 A2c[16*40];     // [xc][r], r = kk*5+q, kk=0..7
    int t = threadIdx.x;
    int ol = t & 31, rg = t >> 5;
    int bid = blockIdx.x;             // (b*CI + i)*4 + kq
    int kq = bid & 3;
    int i  = (bid >> 2) & (CI-1);
    int b  = bid >> 7;
    int k0 = kq*8;
    const float2* asrc = alpha + ((size_t)(b*CI + i))*(N*N);

    // precomputed staging geometry (constant across cx)
    const int trow = t >> 4, txc = t & 15;              // tile: l = t+128j -> row trow+8j
    // A2 staging: 5 elements/thread, e = t + 128*s
    int a2dst[5]; size_t a2src[5];
    #pragma unroll
    for(int s=0;s<5;s++){
        int e = t + 128*s;
        int xcs = e / 40, rs = e - xcs*40;
        int kk = rs / 5, qq = rs - kk*5;
        a2dst[s] = xcs*40 + rs;
        a2src[s] = ((size_t)(i*CO + k0 + kk)*M2 + qq)*N + xcs;
    }

    float2 U[2][4][5];
    #pragma unroll
    for(int s=0;s<2;s++)
        #pragma unroll
        for(int oi=0;oi<4;oi++)
            #pragma unroll
            for(int q=0;q<5;q++) U[s][oi][q] = make_float2(0.f,0.f);

    // prologue: prefetch chunk 0
    float2 pre[16], a2pre[5];
    #pragma unroll
    for(int j=0;j<16;j++) pre[j] = asrc[(trow + 8*j)*N + txc];
    #pragma unroll
    for(int s=0;s<5;s++) a2pre[s] = A2[a2src[s]];

    for(int cx=0; cx<8; cx++){
        __syncthreads();          // prev compute done; LDS reusable
        #pragma unroll
        for(int j=0;j<16;j++) tile[(trow + 8*j)*17 + txc] = pre[j];
        #pragma unroll
        for(int s=0;s<5;s++) A2c[a2dst[s]] = a2pre[s];
        if(cx < 7){
            int x0n = (cx+1)*16;
            #pragma unroll
            for(int j=0;j<16;j++) pre[j] = asrc[(trow + 8*j)*N + x0n + txc];
            #pragma unroll
            for(int s=0;s<5;s++) a2pre[s] = A2[a2src[s] + x0n];
        }
        __syncthreads();
        #pragma unroll 4
        for(int xc=0; xc<16; xc++){
            float2 a2lo[5], a2hi[5];
            const float2* a2row = A2c + xc*40 + rg*5;
            #pragma unroll
            for(int q=0;q<5;q++){ a2lo[q] = a2row[q]; a2hi[q] = a2row[q+20]; }
            #pragma unroll
            for(int oi=0;oi<4;oi++){
                float2 av = tile[(ol+32*oi)*17 + xc];
                #pragma unroll
                for(int q=0;q<5;q++){
                    U[0][oi][q] = cmadd(U[0][oi][q], av, a2lo[q]);
                    U[1][oi][q] = cmadd(U[1][oi][q], av, a2hi[q]);
                }
            }
        }
    }

    // S-phase per k-instance: in-register over 4 o's + 32-lane butterfly
    #pragma unroll
    for(int s=0;s<2;s++){
        int k = k0 + rg + 4*s;
        int ik = i*CO + k;
        float2 S[4][5];
        #pragma unroll
        for(int p=0;p<4;p++)
            #pragma unroll
            for(int q=0;q<5;q++) S[p][q] = make_float2(0.f,0.f);
        #pragma unroll
        for(int oi=0;oi<4;oi++){
            int o = ol + 32*oi;
            const float2* a1 = A1T + (size_t)o*IKP + (size_t)ik*M1;
            float2 a1v[4];
            #pragma unroll
            for(int p=0;p<4;p++) a1v[p] = a1[p];
            #pragma unroll
            for(int p=0;p<4;p++)
                #pragma unroll
                for(int q=0;q<5;q++) S[p][q] = cmadd(S[p][q], a1v[p], U[s][oi][q]);
        }
        #pragma unroll
        for(int m=1;m<32;m<<=1){
            #pragma unroll
            for(int p=0;p<4;p++)
                #pragma unroll
                for(int q=0;q<5;q++){
                    S[p][q].x += __shfl_xor(S[p][q].x, m);
                    S[p][q].y += __shfl_xor(S[p][q].y, m);
                }
        }
        if(ol==0){
            const float* wr0 = wrr + ik*(M1*M2);
            const float* wi0 = wri + ik*(M1*M2);
            float2* dst = res2 + (size_t)(b*CO + k)*(M1*M2);
            #pragma unroll
            for(int p=0;p<4;p++)
                #pragma unroll
                for(int q=0;q<5;q++){
                    float2 w = make_float2(wr0[p*5+q], wi0[p*5+q]);
                    float2 v = cmul(w, S[p][q]);
                    atomicAdd(&dst[p*5+q].x, v.x);
                    atomicAdd(&dst[p*5+q].y, v.y);
                }
        }
    }
}

// x2[b,j,y,x] += (1/N^2) * Re( sum_{c,p,q} res2[b,c,p,q]*E1[c,j,p,y]*E2[c,j,q,x] )
// grid split 4x over y for occupancy: block handles y = 8r + 2*ys + hb
__global__ void __launch_bounds__(256) k_x2(const float2* res2, const float2* E1,
                                            const float2* E2, float* out){
    __shared__ float2 Wt[M1][N];
    __shared__ float2 E1s[M1][N];
    int t = threadIdx.x;
    int ys = blockIdx.x & 3;
    int j = (blockIdx.x >> 2) & 31;
    int b = blockIdx.x >> 7;
    int xx = t & (N-1); int hb = t >> 7;
    float acc[16];
    #pragma unroll
    for(int r=0;r<16;r++) acc[r]=0.f;
    for(int c=0;c<CI;c++){
        int ikcj = c*CO + j;
        __syncthreads();
        #pragma unroll
        for(int s=0;s<2;s++){
            int e = t + 256*s;
            int pp = e >> 7; int xi = e & (N-1);
            float2 w = make_float2(0.f,0.f);
            const float2* r2 = res2 + (size_t)(b*CO + c)*(M1*M2) + pp*M2;
            const float2* e2 = E2 + ((size_t)ikcj*M2)*N + xi;
            #pragma unroll
            for(int q=0;q<M2;q++) w = cmadd(w, r2[q], e2[q*N]);
            Wt[pp][xi] = w;
            E1s[pp][xi] = E1[((size_t)ikcj*M1 + pp)*N + xi];
        }
        __syncthreads();
        float2 wreg[M1];
        #pragma unroll
        for(int p=0;p<M1;p++) wreg[p] = Wt[p][xx];
        #pragma unroll
        for(int r=0;r<16;r++){
            int y = 8*r + 2*ys + hb;
            float s = 0.f;
            #pragma unroll
            for(int p=0;p<M1;p++){
                float2 e = E1s[p][y];
                s += e.x*wreg[p].x - e.y*wreg[p].y;
            }
            acc[r] += s;
        }
    }
    const float sc = 1.0f/((float)N*(float)N);
    size_t base = (size_t)(b*CO + j)*(N*N);
    #pragma unroll
    for(int r=0;r<16;r++){
        size_t idx = base + (size_t)(8*r + 2*ys + hb)*N + xx;
        out[idx] += acc[r]*sc;
    }
}

extern "C" void kernel_launch(void* const* d_in, const int* in_sizes, int n_in,
                              void* d_out, int out_size, void* d_ws, size_t ws_size,
                              hipStream_t stream){
    const float* x    = (const float*)d_in[0];
    const float* wp1r = (const float*)d_in[1];
    const float* wp1i = (const float*)d_in[2];
    const float* wp2r = (const float*)d_in[3];
    const float* wp2i = (const float*)d_in[4];
    const float* wrr  = (const float*)d_in[5];
    const float* wri  = (const float*)d_in[6];
    const float* ty   = (const float*)d_in[7];
    const float* tx   = (const float*)d_in[8];
    float* out = (float*)d_out;
    float2* ws = (float2*)d_ws;

    const size_t NCIMG = (size_t)B*CI*N*N;        // 4194304 complexes
    float2* bufA  = ws;
    float2* alpha = bufA  + NCIMG;
    float2* res1  = alpha + NCIMG;
    float2* A1T   = res1  + NCIMG;                // N*IKP
    float2* A2    = A1T   + (size_t)N*IKP;        // IKQ*N
    float2* W2T   = A2    + (size_t)IKQ*N;        // N*IKP
    float2* E1    = W2T   + (size_t)N*IKP;        // IKP*N
    float2* E2    = E1    + (size_t)IKP*N;        // IKQ*N
    float2* res2  = E2    + (size_t)IKQ*N;        // B*CO*M1*M2

    k_A1T<<<(N*IKP)/256, 256, 0, stream>>>(wp1r, wp1i, ty, A1T);
    k_E  <<<(IKP*N)/256, 256, 0, stream>>>(wp1r, wp1i, ty, E1);
    k_A2 <<<(IKQ*N)/256, 256, 0, stream>>>(wp2r, wp2i, tx, A2);
    k_E  <<<(IKQ*N)/256, 256, 0, stream>>>(wp2r, wp2i, tx, E2);
    k_W2T<<<(IKP*N)/256, 256, 0, stream>>>(wrr, wri, A2, W2T);

    // forward fft2: rows (real in) then cols
    k_fft_rows<0,1,0><<<(B*CI*N)/16, 256, 0, stream>>>((const void*)x, bufA);
    k_fft_cols<0,0,0><<<B*CI*8, 256, 0, stream>>>(bufA, alpha, nullptr);

    hipMemsetAsync(res2, 0, (size_t)B*CO*M1*M2*sizeof(float2), stream);
    k_res1<<<N*N, 256, 0, stream>>>(alpha, A1T, W2T, res1);
    k_S_res2<<<B*CI*4, 128, 0, stream>>>(alpha, A2, A1T, wrr, wri, res2);

    // inverse fft2: rows (1/N) then cols (real out, 1/N)
    k_fft_rows<1,0,1><<<(B*CO*N)/16, 256, 0, stream>>>((const void*)res1, bufA);
    k_fft_cols<1,1,1><<<B*CO*8, 256, 0, stream>>>(bufA, nullptr, out);
    k_x2<<<B*CO*4, 256, 0, stream>>>(res2, E1, E2, out);
}